// Round 12
// baseline (1007.976 us; speedup 1.0000x reference)
//
#include <hip/hip_runtime.h>
#include <stdint.h>

typedef short bfrag __attribute__((ext_vector_type(8)));    // 8 bf16 (4 VGPR)
typedef float facc16 __attribute__((ext_vector_type(16)));  // 32x32 accumulator

__device__ __forceinline__ unsigned short f2bf(float x){
  union { float f; uint32_t u; } v; v.f = x;
  uint32_t r = v.u + 0x7FFFu + ((v.u >> 16) & 1u);   // RNE
  return (unsigned short)(r >> 16);
}
__device__ __forceinline__ float bf2f(unsigned short h){
  union { uint32_t u; float f; } v; v.u = ((uint32_t)h) << 16; return v.f;
}
__device__ __forceinline__ uint32_t pack2(unsigned short a, unsigned short b){
  return (uint32_t)a | ((uint32_t)b << 16);
}

__device__ __forceinline__ void gload_lds16(const void* g, void* l){
  __builtin_amdgcn_global_load_lds(
      (const __attribute__((address_space(1))) void*)g,
      (__attribute__((address_space(3))) void*)l, 16, 0, 0);
}

// ---------------------------------------------------------------------------
// 256x256 4-phase bf16 GEMM, 8 waves (2M x 4N), BK=64, 128 KB LDS dbuf.
// r12 = r11 schedule (counted vmcnt(7), 1/3/3/1 staging, coalesced 8rx128B
// DMA blocks, 0 conflicts) + 32x32x16 MFMA + persistent multi-tile blocks.
//
// 32x32x16 switch: DMA/LDS layout UNCHANGED. ds_read frag(mi|ni, ks):
//   lane (fr5=lane&31, fk1=lane>>5) reads block base + (fr5>>3)*1KB +
//   (fr5&7)*128B + ((2ks+fk1)^(fr5&7))*16B  -> even 8x spread per instr.
// Phase p computes mi=p: 8 MFMA (ks0..3 x ni0..1), A reads 4/phase,
// B (2x4 frags) read once at p0. Phase p reads A blocks {4p..4p+3,
// 16+4p..+3} = G_p -> staging death map identical to r11.
// C/D map (m74/m101): col = lane&31, row = (r&3)+8*(r>>2)+4*(lane>>5).
//
// Persistent: 1D grid (nwg = min(256,total)); block sweeps TPB tiles
// (lin = it*nwg + swz -> x,y,z). Next tile's 15-load prologue issues
// BEFORE the epilogue (lands under C-store burst); re-enter K-loop on
// vmcnt(7)+barrier. Removes the per-epoch pipeline drain.
//
// REMAP=1: A,B are [hi|lo], NT=48 encodes Ah*Bh+Ah*Bl+Al*Bh via
// akt=(kt<16?kt:kt-16), bkt=(kt<32?kt:kt-32). REMAP=0: plain, NT=K/64.
// OUT: 0 = f32 C. 1 = split write hi at [row*2048+col], lo at +1024.
// T1: bijective XCD swizzle (m204) on the 1D block id.
// ---------------------------------------------------------------------------
template<int REMAP, int OUT>
__global__ __launch_bounds__(512, 1)
void gemm256(const unsigned short* __restrict__ A,
             const unsigned short* __restrict__ B,
             void* __restrict__ C,
             int NT, int lda, int ldb, int ldc,
             long abstr, long bbstr, long cbstr,
             int GX, int GY, int TPB)
{
  __shared__ __align__(16) unsigned short lds[2][2][16384];   // 128 KB

  const int tid  = threadIdx.x;
  const int lane = tid & 63;
  const int wv   = tid >> 6;          // 0..7
  const int wm   = wv >> 2;           // 0..1  -> 128 rows
  const int wn   = wv & 3;            // 0..3  -> 64 cols

  // T1: bijective XCD-aware remap (m204), 1D grid
  const int nwg  = gridDim.x;
  const int orig = blockIdx.x;
  const int qd = nwg >> 3, rm = nwg & 7;
  const int xcd = orig & 7, idx = orig >> 3;
  const int swz = (xcd < rm ? xcd * (qd + 1) : rm * (qd + 1) + (xcd - rm) * qd) + idx;

  const int fr5 = lane & 31;
  const int fk1 = lane >> 5;          // 0..1
  // ds_read offsets (shorts) per ks: block-quarter + row + swizzled 16B slot
  int aoff[4];
  #pragma unroll
  for (int ks = 0; ks < 4; ++ks)
    aoff[ks] = (fr5 >> 3) * 512 + (fr5 & 7) * 64 + (((ks * 2 + fk1) ^ (fr5 & 7)) * 8);
  // staging per-thread: row-in-block + swizzled source chunk (r11, unchanged)
  const int r8 = lane >> 3, s8 = lane & 7;
  const int cswz = (s8 ^ r8) * 8;

  const unsigned short *Ab = A, *Bb = B;
  int m0 = 0, n0 = 0, z = 0;

  auto setTile = [&](int it){
    int lin = it * nwg + swz;
    int x = lin % GX; int rest = lin / GX;
    int y = rest % GY; z = rest / GY;
    m0 = x * 256; n0 = y * 256;
    Ab = A + (size_t)z * (size_t)abstr;
    Bb = B + (size_t)z * (size_t)bbstr;
  };

  // stage one A block of group G_p (8 blocks, one per wave)
  auto stageA1 = [&](int buf, int kt, int p){
    int akt = kt; if (REMAP) akt = (kt < 16) ? kt : kt - 16;
    const int ab = 4 * p + (wv & 3) + ((wv >> 2) << 4);
    gload_lds16(Ab + (size_t)(m0 + ab * 8 + r8) * lda + akt * 64 + cswz,
                &lds[buf][0][ab * 512]);
  };
  // stage one quarter of B (8 blocks, one per wave); j = 0..3 covers all 32
  auto stageB = [&](int buf, int kt, int j){
    int bkt = kt; if (REMAP) bkt = (kt < 32) ? kt : kt - 32;
    const int bb = j * 8 + wv;
    gload_lds16(Bb + (size_t)(n0 + bb * 8 + r8) * ldb + bkt * 64 + cswz,
                &lds[buf][1][bb * 512]);
  };
  // prologue: tile0 fully (8/wave), tile1 all but G3 (7/wave) -> 15 in flight
  auto prostage = [&](){
    #pragma unroll
    for (int j = 0; j < 4; ++j) stageB(0, 0, j);
    stageA1(0, 0, 0); stageA1(0, 0, 1); stageA1(0, 0, 2); stageA1(0, 0, 3);
    #pragma unroll
    for (int j = 0; j < 4; ++j) stageB(1, 1, j);
    stageA1(1, 1, 0); stageA1(1, 1, 1); stageA1(1, 1, 2);
  };

  facc16 acc[4][2];

  setTile(0);
  prostage();
  asm volatile("s_waitcnt vmcnt(7)" ::: "memory");    // tile0's 8 landed
  asm volatile("s_barrier" ::: "memory");

  for (int it = 0; it < TPB; ++it){
    #pragma unroll
    for (int a = 0; a < 4; ++a)
      #pragma unroll
      for (int b = 0; b < 2; ++b)
        acc[a][b] = (facc16)(0.f);

    for (int t = 0; t < NT; ++t){
      const int cur = t & 1;
      const unsigned short* la = lds[cur][0];
      const unsigned short* lb = lds[cur][1];
      bfrag bv[2][4];
      #pragma unroll
      for (int p = 0; p < 4; ++p){
        // --- ds_read this phase's fragments ---
        const unsigned short* labase = la + (wm * 16 + p * 4) * 512;
        bfrag a0 = *(const bfrag*)(labase + aoff[0]);
        bfrag a1 = *(const bfrag*)(labase + aoff[1]);
        bfrag a2 = *(const bfrag*)(labase + aoff[2]);
        bfrag a3 = *(const bfrag*)(labase + aoff[3]);
        if (p == 0){
          #pragma unroll
          for (int ni = 0; ni < 2; ++ni){
            const unsigned short* lbbase = lb + (wn * 8 + ni * 4) * 512;
            #pragma unroll
            for (int ks = 0; ks < 4; ++ks)
              bv[ni][ks] = *(const bfrag*)(lbbase + aoff[ks]);
          }
        }
        // --- stage issue (death-region-safe, 1/3/3/1) ---
        if (p == 0 && t + 1 < NT) stageA1(cur ^ 1, t + 1, 3);
        if (p == 1 && t + 2 < NT){ stageB(cur, t + 2, 0); stageB(cur, t + 2, 1); stageA1(cur, t + 2, 0); }
        if (p == 2 && t + 2 < NT){ stageB(cur, t + 2, 2); stageB(cur, t + 2, 3); stageA1(cur, t + 2, 1); }
        if (p == 3 && t + 2 < NT) stageA1(cur, t + 2, 2);

        if (p == 0) asm volatile("s_waitcnt lgkmcnt(8)" ::: "memory");
        asm volatile("s_barrier" ::: "memory");
        asm volatile("s_waitcnt lgkmcnt(0)" ::: "memory");
        __builtin_amdgcn_sched_barrier(0);

        __builtin_amdgcn_s_setprio(1);
        // ks-major; adjacent MFMAs independent (ni pair), dep distance 2
        acc[p][0] = __builtin_amdgcn_mfma_f32_32x32x16_bf16(a0, bv[0][0], acc[p][0], 0, 0, 0);
        acc[p][1] = __builtin_amdgcn_mfma_f32_32x32x16_bf16(a0, bv[1][0], acc[p][1], 0, 0, 0);
        acc[p][0] = __builtin_amdgcn_mfma_f32_32x32x16_bf16(a1, bv[0][1], acc[p][0], 0, 0, 0);
        acc[p][1] = __builtin_amdgcn_mfma_f32_32x32x16_bf16(a1, bv[1][1], acc[p][1], 0, 0, 0);
        acc[p][0] = __builtin_amdgcn_mfma_f32_32x32x16_bf16(a2, bv[0][2], acc[p][0], 0, 0, 0);
        acc[p][1] = __builtin_amdgcn_mfma_f32_32x32x16_bf16(a2, bv[1][2], acc[p][1], 0, 0, 0);
        acc[p][0] = __builtin_amdgcn_mfma_f32_32x32x16_bf16(a3, bv[0][3], acc[p][0], 0, 0, 0);
        acc[p][1] = __builtin_amdgcn_mfma_f32_32x32x16_bf16(a3, bv[1][3], acc[p][1], 0, 0, 0);
        __builtin_amdgcn_s_setprio(0);

        if (p == 3 && t + 1 < NT){
          if (t + 2 < NT) asm volatile("s_waitcnt vmcnt(7)" ::: "memory");
          else            asm volatile("s_waitcnt vmcnt(0)" ::: "memory");
        }
        asm volatile("s_barrier" ::: "memory");
      }
    }

    // save this tile's output coords, then issue next tile's prologue so the
    // 15 loads land under the epilogue stores
    const int cm0 = m0, cn0 = n0;
    const size_t cco = (size_t)z * (size_t)cbstr;
    const bool more = (it + 1 < TPB);
    if (more){ setTile(it + 1); prostage(); }

    #pragma unroll
    for (int mi = 0; mi < 4; ++mi)
      #pragma unroll
      for (int ni = 0; ni < 2; ++ni)
        #pragma unroll
        for (int r = 0; r < 16; ++r){
          const int row = cm0 + wm * 128 + mi * 32 + (r & 3) + 8 * (r >> 2) + 4 * fk1;
          const int col = cn0 + wn * 64 + ni * 32 + fr5;
          const float v = acc[mi][ni][r];
          if constexpr (OUT == 0){
            ((float*)C)[cco + (size_t)row * ldc + col] = v;
          } else {
            unsigned short* o = (unsigned short*)C;
            const unsigned short h = f2bf(v);
            o[(size_t)row * 2048 + col]        = h;
            o[(size_t)row * 2048 + 1024 + col] = f2bf(v - bf2f(h));
          }
        }

    if (more){
      asm volatile("s_waitcnt vmcnt(7)" ::: "memory");
      asm volatile("s_barrier" ::: "memory");
    }
  }
}

// W[e][n] f32 -> Wt[n][2048] = [Wt_h | Wt_l] bf16
__global__ __launch_bounds__(256)
void wtprep_kernel(const float* __restrict__ W, unsigned short* __restrict__ Wt)
{
  __shared__ float tile[64][65];
  const int e0 = blockIdx.x * 64, n0 = blockIdx.y * 64;
  const int t = threadIdx.x;
  const int r = t >> 2, cq = t & 3;
  #pragma unroll
  for (int i = 0; i < 4; ++i){
    float4 f = *(const float4*)(W + (size_t)(e0 + r) * 1024 + n0 + cq*16 + i*4);
    tile[r][cq*16 + i*4 + 0] = f.x;
    tile[r][cq*16 + i*4 + 1] = f.y;
    tile[r][cq*16 + i*4 + 2] = f.z;
    tile[r][cq*16 + i*4 + 3] = f.w;
  }
  __syncthreads();
  unsigned short h[16], l[16];
  #pragma unroll
  for (int i = 0; i < 16; ++i){
    float v = tile[cq*16 + i][r];
    h[i] = f2bf(v);
    l[i] = f2bf(v - bf2f(h[i]));
  }
  uint4 ha, hb, la4, lb4;
  ha.x=pack2(h[0],h[1]);   ha.y=pack2(h[2],h[3]);   ha.z=pack2(h[4],h[5]);   ha.w=pack2(h[6],h[7]);
  hb.x=pack2(h[8],h[9]);   hb.y=pack2(h[10],h[11]); hb.z=pack2(h[12],h[13]); hb.w=pack2(h[14],h[15]);
  la4.x=pack2(l[0],l[1]);  la4.y=pack2(l[2],l[3]);  la4.z=pack2(l[4],l[5]);  la4.w=pack2(l[6],l[7]);
  lb4.x=pack2(l[8],l[9]);  lb4.y=pack2(l[10],l[11]);lb4.z=pack2(l[12],l[13]);lb4.w=pack2(l[14],l[15]);
  size_t o = (size_t)(n0 + r) * 2048 + e0 + cq*16;
  *(uint4*)(Wt + o)          = ha;
  *(uint4*)(Wt + o + 8)      = hb;
  *(uint4*)(Wt + o + 1024)   = la4;
  *(uint4*)(Wt + o + 1032)   = lb4;
}

// q rows f32 [R][1024] -> qsplit[R][2048] = [q_h | q_l]
__global__ __launch_bounds__(256)
void qprep_kernel(const float* __restrict__ q, unsigned short* __restrict__ qs)
{
  const int gid = blockIdx.x * 256 + threadIdx.x;
  const int row = gid >> 7;
  const int c8  = (gid & 127) * 8;
  const float* src = q + (size_t)row * 1024 + c8;
  float4 f0 = *(const float4*)src;
  float4 f1 = *(const float4*)(src + 4);
  float vs[8] = {f0.x, f0.y, f0.z, f0.w, f1.x, f1.y, f1.z, f1.w};
  unsigned short h[8], l[8];
  #pragma unroll
  for (int i = 0; i < 8; ++i){ h[i] = f2bf(vs[i]); l[i] = f2bf(vs[i] - bf2f(h[i])); }
  uint4 hv, lv;
  hv.x=pack2(h[0],h[1]); hv.y=pack2(h[2],h[3]); hv.z=pack2(h[4],h[5]); hv.w=pack2(h[6],h[7]);
  lv.x=pack2(l[0],l[1]); lv.y=pack2(l[2],l[3]); lv.z=pack2(l[4],l[5]); lv.w=pack2(l[6],l[7]);
  size_t o = (size_t)row * 2048 + c8;
  *(uint4*)(qs + o)        = hv;
  *(uint4*)(qs + o + 1024) = lv;
}

// k[b][kv][e] f32 -> ksplit[b][kv][2048] = [k_h | k_l] and kT[b][e][kv] (hi)
__global__ __launch_bounds__(256)
void kprep_kernel(const float* __restrict__ kin, unsigned short* __restrict__ ks,
                  unsigned short* __restrict__ kT)
{
  __shared__ float tile[64][65];
  const int bz = blockIdx.z;
  const float* kb = kin + (size_t)bz * 2048 * 1024;
  unsigned short* ksb = ks + (size_t)bz * 2048 * 2048;
  unsigned short* kTb = kT + (size_t)bz * 1024 * 2048;
  const int kv0 = blockIdx.x * 64, e0 = blockIdx.y * 64;
  const int t = threadIdx.x;
  const int r = t >> 2, cq = t & 3;
  #pragma unroll
  for (int i = 0; i < 4; ++i){
    float4 f = *(const float4*)(kb + (size_t)(kv0 + r) * 1024 + e0 + cq*16 + i*4);
    unsigned short h0=f2bf(f.x), h1=f2bf(f.y), h2=f2bf(f.z), h3=f2bf(f.w);
    uint2 hv, lv;
    hv.x = pack2(h0, h1); hv.y = pack2(h2, h3);
    lv.x = pack2(f2bf(f.x - bf2f(h0)), f2bf(f.y - bf2f(h1)));
    lv.y = pack2(f2bf(f.z - bf2f(h2)), f2bf(f.w - bf2f(h3)));
    size_t o = (size_t)(kv0 + r) * 2048 + e0 + cq*16 + i*4;
    *(uint2*)(ksb + o)        = hv;
    *(uint2*)(ksb + o + 1024) = lv;
    tile[r][cq*16 + i*4 + 0] = f.x;
    tile[r][cq*16 + i*4 + 1] = f.y;
    tile[r][cq*16 + i*4 + 2] = f.z;
    tile[r][cq*16 + i*4 + 3] = f.w;
  }
  __syncthreads();
  unsigned short h[16];
  #pragma unroll
  for (int i = 0; i < 16; ++i) h[i] = f2bf(tile[cq*16 + i][r]);
  uint4 va, vb;
  va.x=pack2(h[0],h[1]);  va.y=pack2(h[2],h[3]);   va.z=pack2(h[4],h[5]);   va.w=pack2(h[6],h[7]);
  vb.x=pack2(h[8],h[9]);  vb.y=pack2(h[10],h[11]); vb.z=pack2(h[12],h[13]); vb.w=pack2(h[14],h[15]);
  size_t o = (size_t)(e0 + r) * 2048 + kv0 + cq*16;
  *(uint4*)(kTb + o)     = va;
  *(uint4*)(kTb + o + 8) = vb;
}

// exact row softmax over 2048 f32, then * mask, -> bf16
__global__ __launch_bounds__(256)
void softmax_kernel(const float* __restrict__ S, const int* __restrict__ mask,
                    unsigned short* __restrict__ P)
{
  const int row = blockIdx.x;
  const float* s = S + (size_t)row * 2048;
  const int* mk = mask + (size_t)row * 2048;
  unsigned short* p = P + (size_t)row * 2048;
  const int t = threadIdx.x;
  float4 v0 = ((const float4*)s)[t];
  float4 v1 = ((const float4*)s)[t + 256];
  float m = fmaxf(fmaxf(fmaxf(v0.x, v0.y), fmaxf(v0.z, v0.w)),
                  fmaxf(fmaxf(v1.x, v1.y), fmaxf(v1.z, v1.w)));
  #pragma unroll
  for (int off = 32; off > 0; off >>= 1) m = fmaxf(m, __shfl_xor(m, off));
  __shared__ float rmax[4], rsum[4];
  const int wid = t >> 6;
  if ((t & 63) == 0) rmax[wid] = m;
  __syncthreads();
  m = fmaxf(fmaxf(rmax[0], rmax[1]), fmaxf(rmax[2], rmax[3]));
  float e0 = __expf(v0.x - m), e1 = __expf(v0.y - m), e2 = __expf(v0.z - m), e3 = __expf(v0.w - m);
  float e4 = __expf(v1.x - m), e5 = __expf(v1.y - m), e6 = __expf(v1.z - m), e7 = __expf(v1.w - m);
  float ssum = ((e0 + e1) + (e2 + e3)) + ((e4 + e5) + (e6 + e7));
  #pragma unroll
  for (int off = 32; off > 0; off >>= 1) ssum += __shfl_xor(ssum, off);
  if ((t & 63) == 0) rsum[wid] = ssum;
  __syncthreads();
  float inv = 1.f / (rsum[0] + rsum[1] + rsum[2] + rsum[3]);
  int4 m0 = ((const int4*)mk)[t];
  int4 m1 = ((const int4*)mk)[t + 256];
  ushort4 o0, o1;
  o0.x = f2bf(e0 * inv * (float)m0.x);
  o0.y = f2bf(e1 * inv * (float)m0.y);
  o0.z = f2bf(e2 * inv * (float)m0.z);
  o0.w = f2bf(e3 * inv * (float)m0.w);
  o1.x = f2bf(e4 * inv * (float)m1.x);
  o1.y = f2bf(e5 * inv * (float)m1.y);
  o1.z = f2bf(e6 * inv * (float)m1.z);
  o1.w = f2bf(e7 * inv * (float)m1.w);
  ((ushort4*)p)[t]       = o0;
  ((ushort4*)p)[t + 256] = o1;
}

extern "C" void kernel_launch(void* const* d_in, const int* in_sizes, int n_in,
                              void* d_out, int out_size, void* d_ws, size_t ws_size,
                              hipStream_t stream)
{
  (void)in_sizes; (void)n_in; (void)out_size;
  const float* kin  = (const float*)d_in[0];
  const float* qin  = (const float*)d_in[1];
  const float* Win  = (const float*)d_in[2];
  const int*   mask = (const int*)d_in[3];

  // ws: Wt (4MB) | per-batch { qsplit 8 | qwsplit 8 | ksplit 8 | kT 4 | S 16 | P 8 } = 52MB
  int bpc = 1;
  {
    const size_t per_b = (size_t)2048*2048*2*3 + (size_t)1024*2048*2
                       + (size_t)2048*2048*4 + (size_t)2048*2048*2;
    const size_t fixed = (size_t)1024*2048*2;
    const int cands[5] = {16, 8, 4, 2, 1};
    for (int i = 0; i < 5; ++i){
      if (fixed + (size_t)cands[i] * per_b <= ws_size){ bpc = cands[i]; break; }
    }
  }
  unsigned short* Wt      = (unsigned short*)d_ws;
  unsigned short* qsplit  = Wt + (size_t)1024*2048;
  unsigned short* qwsplit = qsplit  + (size_t)bpc*2048*2048;
  unsigned short* ksplit  = qwsplit + (size_t)bpc*2048*2048;
  unsigned short* kT      = ksplit  + (size_t)bpc*2048*2048;
  float*          Sb      = (float*)(kT + (size_t)bpc*1024*2048);
  unsigned short* Pb      = (unsigned short*)(Sb + (size_t)bpc*2048*2048);

  wtprep_kernel<<<dim3(16, 16, 1), 256, 0, stream>>>(Win, Wt);

  // persistent grid helper: nwg = min(256, total), TPB = total/nwg
  auto dims = [](int total, int& nwg, int& tpb){
    nwg = total < 256 ? total : 256;
    tpb = total / nwg;
  };

  for (int cb = 0; cb < 16; cb += bpc){
    qprep_kernel<<<dim3(bpc * 1024, 1, 1), 256, 0, stream>>>(
        qin + (size_t)cb * 2048 * 1024, qsplit);

    // K1: qw = q @ W  (3-pass split via remap, NT=48) -> qwsplit [h|l]
    {
      int GX = bpc * 8, GY = 4, nwg, tpb; dims(GX * GY, nwg, tpb);
      gemm256<1, 1><<<dim3(nwg, 1, 1), 512, 0, stream>>>(
          qsplit, Wt, qwsplit, 48, 2048, 2048, 0, 0, 0, 0, GX, GY, tpb);
    }

    kprep_kernel<<<dim3(32, 16, bpc), 256, 0, stream>>>(
        kin + (size_t)cb * 2048 * 1024, ksplit, kT);

    // K2: S = qw @ k^T (3-pass split via remap, NT=48), batched
    {
      int GX = 8, GY = 8, nwg, tpb; dims(GX * GY * bpc, nwg, tpb);
      gemm256<1, 0><<<dim3(nwg, 1, 1), 512, 0, stream>>>(
          qwsplit, ksplit, Sb, 48, 2048, 2048, 2048,
          (long)2048 * 2048, (long)2048 * 2048, (long)2048 * 2048, GX, GY, tpb);
    }

    // K3: row softmax * mask -> P (bf16)
    softmax_kernel<<<dim3(bpc * 2048, 1, 1), 256, 0, stream>>>(
        Sb, mask + (size_t)cb * 2048 * 2048, Pb);

    // K4: O = P @ kT^T (plain, NT=32), batched -> d_out
    {
      int GX = 8, GY = 4, nwg, tpb; dims(GX * GY * bpc, nwg, tpb);
      gemm256<0, 0><<<dim3(nwg, 1, 1), 512, 0, stream>>>(
          Pb, kT, (float*)d_out + (size_t)cb * 2048 * 1024, 32, 2048, 2048, 1024,
          (long)2048 * 2048, (long)1024 * 2048, (long)2048 * 1024, GX, GY, tpb);
    }
  }
}

// Round 13
// 941.180 us; speedup vs baseline: 1.0710x; 1.0710x over previous
//
#include <hip/hip_runtime.h>
#include <stdint.h>

typedef short bfrag __attribute__((ext_vector_type(8)));   // 8 bf16 (4 VGPR)
typedef float facc4 __attribute__((ext_vector_type(4)));   // MFMA accumulator

__device__ __forceinline__ unsigned short f2bf(float x){
  union { float f; uint32_t u; } v; v.f = x;
  uint32_t r = v.u + 0x7FFFu + ((v.u >> 16) & 1u);   // RNE
  return (unsigned short)(r >> 16);
}
__device__ __forceinline__ float bf2f(unsigned short h){
  union { uint32_t u; float f; } v; v.u = ((uint32_t)h) << 16; return v.f;
}
__device__ __forceinline__ uint32_t pack2(unsigned short a, unsigned short b){
  return (uint32_t)a | ((uint32_t)b << 16);
}

__device__ __forceinline__ void gload_lds16(const void* g, void* l){
  __builtin_amdgcn_global_load_lds(
      (const __attribute__((address_space(1))) void*)g,
      (__attribute__((address_space(3))) void*)l, 16, 0, 0);
}

// ---------------------------------------------------------------------------
// 256x256 4-phase bf16 GEMM, 8 waves (2M x 4N), BK=64, 128 KB LDS dbuf.
// == r11 (K2 412us, 0 conflicts) + intra-tile A-read hoisting ==
//
// LDS block layout (r11, verified 0-conflict): tile = 32 blocks of 1KB;
// block b = rows b*8..+7 x BK=64; row r's 16B slot s holds k-chunk (s^r)
// (same involution on DMA source and ds_read -- rule #21). gload = 8 rows
// x full 128B lines.  16x16x32 MFMA; frag reads 2-way max (free, m136).
//
// r13 change (ONLY): phase p+1's 4 A-frag ds_reads move from "pre-BARRIER1
// of phase p+1" to "post-lgkm0 of phase p" (pinned DS_READ x4 then MFMA x16
// via sched_group_barrier). They retire under p's MFMA window -> phases
// 1-3 have zero pre-MFMA LDS wait. Death-map re-audit: G1 read@p0-window,
// staged@p2; G2 @p1,@p3; G3 @p2,@(t+1).p0 -- >=2 barriers apart, race-free.
// Staging map, vmcnt(7) gate (T4), barriers, lgkm(8) stagger: r11-identical.
//
// REMAP=1: A,B are [hi|lo], NT=48 encodes Ah*Bh+Ah*Bl+Al*Bh via
// akt=(kt<16?kt:kt-16), bkt=(kt<32?kt:kt-32). REMAP=0: plain, NT=K/64.
// OUT: 0 = f32 C. 1 = split write hi at [row*2048+col], lo at +1024.
// T1: bijective XCD swizzle (m204) on flattened block id.
// ---------------------------------------------------------------------------
template<int REMAP, int OUT>
__global__ __launch_bounds__(512, 1)
void gemm256(const unsigned short* __restrict__ A,
             const unsigned short* __restrict__ B,
             void* __restrict__ C,
             int NT, int lda, int ldb, int ldc,
             long abstr, long bbstr, long cbstr)
{
  __shared__ __align__(16) unsigned short lds[2][2][16384];   // 128 KB

  const int tid  = threadIdx.x;
  const int lane = tid & 63;
  const int wv   = tid >> 6;          // 0..7
  const int wm   = wv >> 2;           // 0..1  -> 128 rows
  const int wn   = wv & 3;            // 0..3  -> 64 cols

  // T1: bijective XCD-aware remap of the flattened block id (m204)
  const int gx = gridDim.x, gy = gridDim.y;
  const int nwg  = gx * gy * (int)gridDim.z;
  const int orig = blockIdx.x + gx * (blockIdx.y + gy * blockIdx.z);
  const int qd = nwg >> 3, rm = nwg & 7;
  const int xcd = orig & 7, idx = orig >> 3;
  const int swz = (xcd < rm ? xcd * (qd + 1) : rm * (qd + 1) + (xcd - rm) * qd) + idx;
  const int m0 = (swz % gx) * 256;
  const int rest = swz / gx;
  const int n0 = (rest % gy) * 256;
  const int z  = rest / gy;

  const unsigned short* Ab = A + (size_t)z * (size_t)abstr;
  const unsigned short* Bb = B + (size_t)z * (size_t)bbstr;

  const int fr  = lane & 15;
  const int fkc = lane >> 4;          // 0..3
  // ds_read per-thread offsets (shorts): block-half + row + swizzled slot
  const int rlow = fr & 7, rhi = fr >> 3;
  const int aoff0 = rhi * 512 + rlow * 64 + ((fkc ^ rlow)) * 8;        // ks=0
  const int aoff1 = rhi * 512 + rlow * 64 + (((4 | fkc) ^ rlow)) * 8;  // ks=1
  // staging per-thread: row-in-block + swizzled source chunk
  const int r8 = lane >> 3, s8 = lane & 7;
  const int cswz = (s8 ^ r8) * 8;     // element offset within 128B row-slice

  // stage one A block of group G_p (8 blocks, one per wave)
  auto stageA1 = [&](int buf, int kt, int p){
    int akt = kt; if (REMAP) akt = (kt < 16) ? kt : kt - 16;
    const int ab = 4 * p + (wv & 3) + ((wv >> 2) << 4);
    gload_lds16(Ab + (size_t)(m0 + ab * 8 + r8) * lda + akt * 64 + cswz,
                &lds[buf][0][ab * 512]);
  };
  // stage one quarter of B (8 blocks, one per wave); j = 0..3 covers all 32
  auto stageB = [&](int buf, int kt, int j){
    int bkt = kt; if (REMAP) bkt = (kt < 32) ? kt : kt - 32;
    const int bb = j * 8 + wv;
    gload_lds16(Bb + (size_t)(n0 + bb * 8 + r8) * ldb + bkt * 64 + cswz,
                &lds[buf][1][bb * 512]);
  };

  facc4 acc[8][4];
  #pragma unroll
  for (int a = 0; a < 8; ++a)
    #pragma unroll
    for (int b = 0; b < 4; ++b)
      acc[a][b] = (facc4){0.f, 0.f, 0.f, 0.f};

  // prologue: tile0 fully (8/wave), tile1 all but G3 (7/wave) -> 15 in flight
  #pragma unroll
  for (int j = 0; j < 4; ++j) stageB(0, 0, j);
  stageA1(0, 0, 0); stageA1(0, 0, 1); stageA1(0, 0, 2); stageA1(0, 0, 3);
  if (NT > 1){
    #pragma unroll
    for (int j = 0; j < 4; ++j) stageB(1, 1, j);
    stageA1(1, 1, 0); stageA1(1, 1, 1); stageA1(1, 1, 2);
    asm volatile("s_waitcnt vmcnt(7)" ::: "memory");    // tile0's 8 landed
  } else {
    asm volatile("s_waitcnt vmcnt(0)" ::: "memory");
  }
  asm volatile("s_barrier" ::: "memory");

  #define RDA(mi, o) (*(const bfrag*)(la + (wm * 8 + (mi)) * 1024 + (o)))
  #define RDB(ni, o) (*(const bfrag*)(lb + (wn * 4 + (ni)) * 1024 + (o)))

  // 16-MFMA cluster, ks-major (8 independent then 8 dependent), setprio'd
  #define MFMA16(MI, f00, f01, f10, f11)                                      \
    __builtin_amdgcn_s_setprio(1);                                            \
    _Pragma("unroll")                                                         \
    for (int ni = 0; ni < 4; ++ni){                                           \
      acc[MI][ni]   = __builtin_amdgcn_mfma_f32_16x16x32_bf16(f00, bv[ni][0], acc[MI][ni],   0, 0, 0); \
      acc[MI+1][ni] = __builtin_amdgcn_mfma_f32_16x16x32_bf16(f10, bv[ni][0], acc[MI+1][ni], 0, 0, 0); \
    }                                                                         \
    _Pragma("unroll")                                                         \
    for (int ni = 0; ni < 4; ++ni){                                           \
      acc[MI][ni]   = __builtin_amdgcn_mfma_f32_16x16x32_bf16(f01, bv[ni][1], acc[MI][ni],   0, 0, 0); \
      acc[MI+1][ni] = __builtin_amdgcn_mfma_f32_16x16x32_bf16(f11, bv[ni][1], acc[MI+1][ni], 0, 0, 0); \
    }                                                                         \
    __builtin_amdgcn_s_setprio(0);

  // pin: 4 hoisted DS reads first, then the 16 MFMAs (T19 masks)
  #define PIN_DS4_MFMA16()                                                    \
    __builtin_amdgcn_sched_group_barrier(0x100, 4, 0);                        \
    __builtin_amdgcn_sched_group_barrier(0x8, 16, 0);

  for (int t = 0; t < NT; ++t){
    const int cur = t & 1;
    const unsigned short* la = lds[cur][0];
    const unsigned short* lb = lds[cur][1];
    bfrag bv[4][2];
    bfrag ac0, ac1, ac2, ac3;   // phase-current A frags
    bfrag an0, an1, an2, an3;   // hoisted next-phase A frags

    // ---- phase 0 ----
    ac0 = RDA(0, aoff0); ac1 = RDA(0, aoff1);
    ac2 = RDA(1, aoff0); ac3 = RDA(1, aoff1);
    #pragma unroll
    for (int ni = 0; ni < 4; ++ni){
      bv[ni][0] = RDB(ni, aoff0);
      bv[ni][1] = RDB(ni, aoff1);
    }
    if (t + 1 < NT) stageA1(cur ^ 1, t + 1, 3);
    asm volatile("s_waitcnt lgkmcnt(8)" ::: "memory");
    asm volatile("s_barrier" ::: "memory");
    asm volatile("s_waitcnt lgkmcnt(0)" ::: "memory");
    __builtin_amdgcn_sched_barrier(0);
    an0 = RDA(2, aoff0); an1 = RDA(2, aoff1);          // hoist phase-1 reads
    an2 = RDA(3, aoff0); an3 = RDA(3, aoff1);
    MFMA16(0, ac0, ac1, ac2, ac3)
    PIN_DS4_MFMA16()
    asm volatile("s_barrier" ::: "memory");

    // ---- phase 1 ----
    if (t + 2 < NT){ stageB(cur, t + 2, 0); stageB(cur, t + 2, 1); stageA1(cur, t + 2, 0); }
    asm volatile("s_barrier" ::: "memory");
    asm volatile("s_waitcnt lgkmcnt(0)" ::: "memory");
    __builtin_amdgcn_sched_barrier(0);
    ac0 = RDA(4, aoff0); ac1 = RDA(4, aoff1);          // hoist phase-2 reads
    ac2 = RDA(5, aoff0); ac3 = RDA(5, aoff1);
    MFMA16(2, an0, an1, an2, an3)
    PIN_DS4_MFMA16()
    asm volatile("s_barrier" ::: "memory");

    // ---- phase 2 ----
    if (t + 2 < NT){ stageB(cur, t + 2, 2); stageB(cur, t + 2, 3); stageA1(cur, t + 2, 1); }
    asm volatile("s_barrier" ::: "memory");
    asm volatile("s_waitcnt lgkmcnt(0)" ::: "memory");
    __builtin_amdgcn_sched_barrier(0);
    an0 = RDA(6, aoff0); an1 = RDA(6, aoff1);          // hoist phase-3 reads
    an2 = RDA(7, aoff0); an3 = RDA(7, aoff1);
    MFMA16(4, ac0, ac1, ac2, ac3)
    PIN_DS4_MFMA16()
    asm volatile("s_barrier" ::: "memory");

    // ---- phase 3 ----
    if (t + 2 < NT) stageA1(cur, t + 2, 2);
    asm volatile("s_barrier" ::: "memory");
    asm volatile("s_waitcnt lgkmcnt(0)" ::: "memory");
    __builtin_amdgcn_sched_barrier(0);
    MFMA16(6, an0, an1, an2, an3)
    if (t + 1 < NT){
      if (t + 2 < NT) asm volatile("s_waitcnt vmcnt(7)" ::: "memory");
      else            asm volatile("s_waitcnt vmcnt(0)" ::: "memory");
    }
    asm volatile("s_barrier" ::: "memory");
  }

  #undef PIN_DS4_MFMA16
  #undef MFMA16
  #undef RDB
  #undef RDA

  #pragma unroll
  for (int mi = 0; mi < 8; ++mi)
    #pragma unroll
    for (int ni = 0; ni < 4; ++ni)
      #pragma unroll
      for (int j = 0; j < 4; ++j){
        const int row = m0 + wm * 128 + mi * 16 + fkc * 4 + j;
        const int col = n0 + wn * 64 + ni * 16 + fr;
        const float v = acc[mi][ni][j];
        if constexpr (OUT == 0){
          ((float*)C)[(size_t)z * (size_t)cbstr + (size_t)row * ldc + col] = v;
        } else {
          unsigned short* o = (unsigned short*)C;
          const unsigned short h = f2bf(v);
          o[(size_t)row * 2048 + col]        = h;
          o[(size_t)row * 2048 + 1024 + col] = f2bf(v - bf2f(h));
        }
      }
}

// W[e][n] f32 -> Wt[n][2048] = [Wt_h | Wt_l] bf16
__global__ __launch_bounds__(256)
void wtprep_kernel(const float* __restrict__ W, unsigned short* __restrict__ Wt)
{
  __shared__ float tile[64][65];
  const int e0 = blockIdx.x * 64, n0 = blockIdx.y * 64;
  const int t = threadIdx.x;
  const int r = t >> 2, cq = t & 3;
  #pragma unroll
  for (int i = 0; i < 4; ++i){
    float4 f = *(const float4*)(W + (size_t)(e0 + r) * 1024 + n0 + cq*16 + i*4);
    tile[r][cq*16 + i*4 + 0] = f.x;
    tile[r][cq*16 + i*4 + 1] = f.y;
    tile[r][cq*16 + i*4 + 2] = f.z;
    tile[r][cq*16 + i*4 + 3] = f.w;
  }
  __syncthreads();
  unsigned short h[16], l[16];
  #pragma unroll
  for (int i = 0; i < 16; ++i){
    float v = tile[cq*16 + i][r];
    h[i] = f2bf(v);
    l[i] = f2bf(v - bf2f(h[i]));
  }
  uint4 ha, hb, la4, lb4;
  ha.x=pack2(h[0],h[1]);   ha.y=pack2(h[2],h[3]);   ha.z=pack2(h[4],h[5]);   ha.w=pack2(h[6],h[7]);
  hb.x=pack2(h[8],h[9]);   hb.y=pack2(h[10],h[11]); hb.z=pack2(h[12],h[13]); hb.w=pack2(h[14],h[15]);
  la4.x=pack2(l[0],l[1]);  la4.y=pack2(l[2],l[3]);  la4.z=pack2(l[4],l[5]);  la4.w=pack2(l[6],l[7]);
  lb4.x=pack2(l[8],l[9]);  lb4.y=pack2(l[10],l[11]);lb4.z=pack2(l[12],l[13]);lb4.w=pack2(l[14],l[15]);
  size_t o = (size_t)(n0 + r) * 2048 + e0 + cq*16;
  *(uint4*)(Wt + o)          = ha;
  *(uint4*)(Wt + o + 8)      = hb;
  *(uint4*)(Wt + o + 1024)   = la4;
  *(uint4*)(Wt + o + 1032)   = lb4;
}

// q rows f32 [R][1024] -> qsplit[R][2048] = [q_h | q_l]
__global__ __launch_bounds__(256)
void qprep_kernel(const float* __restrict__ q, unsigned short* __restrict__ qs)
{
  const int gid = blockIdx.x * 256 + threadIdx.x;
  const int row = gid >> 7;
  const int c8  = (gid & 127) * 8;
  const float* src = q + (size_t)row * 1024 + c8;
  float4 f0 = *(const float4*)src;
  float4 f1 = *(const float4*)(src + 4);
  float vs[8] = {f0.x, f0.y, f0.z, f0.w, f1.x, f1.y, f1.z, f1.w};
  unsigned short h[8], l[8];
  #pragma unroll
  for (int i = 0; i < 8; ++i){ h[i] = f2bf(vs[i]); l[i] = f2bf(vs[i] - bf2f(h[i])); }
  uint4 hv, lv;
  hv.x=pack2(h[0],h[1]); hv.y=pack2(h[2],h[3]); hv.z=pack2(h[4],h[5]); hv.w=pack2(h[6],h[7]);
  lv.x=pack2(l[0],l[1]); lv.y=pack2(l[2],l[3]); lv.z=pack2(l[4],l[5]); lv.w=pack2(l[6],l[7]);
  size_t o = (size_t)row * 2048 + c8;
  *(uint4*)(qs + o)        = hv;
  *(uint4*)(qs + o + 1024) = lv;
}

// k[b][kv][e] f32 -> ksplit[b][kv][2048] = [k_h | k_l] and kT[b][e][kv] (hi)
__global__ __launch_bounds__(256)
void kprep_kernel(const float* __restrict__ kin, unsigned short* __restrict__ ks,
                  unsigned short* __restrict__ kT)
{
  __shared__ float tile[64][65];
  const int bz = blockIdx.z;
  const float* kb = kin + (size_t)bz * 2048 * 1024;
  unsigned short* ksb = ks + (size_t)bz * 2048 * 2048;
  unsigned short* kTb = kT + (size_t)bz * 1024 * 2048;
  const int kv0 = blockIdx.x * 64, e0 = blockIdx.y * 64;
  const int t = threadIdx.x;
  const int r = t >> 2, cq = t & 3;
  #pragma unroll
  for (int i = 0; i < 4; ++i){
    float4 f = *(const float4*)(kb + (size_t)(kv0 + r) * 1024 + e0 + cq*16 + i*4);
    unsigned short h0=f2bf(f.x), h1=f2bf(f.y), h2=f2bf(f.z), h3=f2bf(f.w);
    uint2 hv, lv;
    hv.x = pack2(h0, h1); hv.y = pack2(h2, h3);
    lv.x = pack2(f2bf(f.x - bf2f(h0)), f2bf(f.y - bf2f(h1)));
    lv.y = pack2(f2bf(f.z - bf2f(h2)), f2bf(f.w - bf2f(h3)));
    size_t o = (size_t)(kv0 + r) * 2048 + e0 + cq*16 + i*4;
    *(uint2*)(ksb + o)        = hv;
    *(uint2*)(ksb + o + 1024) = lv;
    tile[r][cq*16 + i*4 + 0] = f.x;
    tile[r][cq*16 + i*4 + 1] = f.y;
    tile[r][cq*16 + i*4 + 2] = f.z;
    tile[r][cq*16 + i*4 + 3] = f.w;
  }
  __syncthreads();
  unsigned short h[16];
  #pragma unroll
  for (int i = 0; i < 16; ++i) h[i] = f2bf(tile[cq*16 + i][r]);
  uint4 va, vb;
  va.x=pack2(h[0],h[1]);  va.y=pack2(h[2],h[3]);   va.z=pack2(h[4],h[5]);   va.w=pack2(h[6],h[7]);
  vb.x=pack2(h[8],h[9]);  vb.y=pack2(h[10],h[11]); vb.z=pack2(h[12],h[13]); vb.w=pack2(h[14],h[15]);
  size_t o = (size_t)(e0 + r) * 2048 + kv0 + cq*16;
  *(uint4*)(kTb + o)     = va;
  *(uint4*)(kTb + o + 8) = vb;
}

// exact row softmax over 2048 f32, then * mask, -> bf16
__global__ __launch_bounds__(256)
void softmax_kernel(const float* __restrict__ S, const int* __restrict__ mask,
                    unsigned short* __restrict__ P)
{
  const int row = blockIdx.x;
  const float* s = S + (size_t)row * 2048;
  const int* mk = mask + (size_t)row * 2048;
  unsigned short* p = P + (size_t)row * 2048;
  const int t = threadIdx.x;
  float4 v0 = ((const float4*)s)[t];
  float4 v1 = ((const float4*)s)[t + 256];
  float m = fmaxf(fmaxf(fmaxf(v0.x, v0.y), fmaxf(v0.z, v0.w)),
                  fmaxf(fmaxf(v1.x, v1.y), fmaxf(v1.z, v1.w)));
  #pragma unroll
  for (int off = 32; off > 0; off >>= 1) m = fmaxf(m, __shfl_xor(m, off));
  __shared__ float rmax[4], rsum[4];
  const int wid = t >> 6;
  if ((t & 63) == 0) rmax[wid] = m;
  __syncthreads();
  m = fmaxf(fmaxf(rmax[0], rmax[1]), fmaxf(rmax[2], rmax[3]));
  float e0 = __expf(v0.x - m), e1 = __expf(v0.y - m), e2 = __expf(v0.z - m), e3 = __expf(v0.w - m);
  float e4 = __expf(v1.x - m), e5 = __expf(v1.y - m), e6 = __expf(v1.z - m), e7 = __expf(v1.w - m);
  float ssum = ((e0 + e1) + (e2 + e3)) + ((e4 + e5) + (e6 + e7));
  #pragma unroll
  for (int off = 32; off > 0; off >>= 1) ssum += __shfl_xor(ssum, off);
  if ((t & 63) == 0) rsum[wid] = ssum;
  __syncthreads();
  float inv = 1.f / (rsum[0] + rsum[1] + rsum[2] + rsum[3]);
  int4 m0 = ((const int4*)mk)[t];
  int4 m1 = ((const int4*)mk)[t + 256];
  ushort4 o0, o1;
  o0.x = f2bf(e0 * inv * (float)m0.x);
  o0.y = f2bf(e1 * inv * (float)m0.y);
  o0.z = f2bf(e2 * inv * (float)m0.z);
  o0.w = f2bf(e3 * inv * (float)m0.w);
  o1.x = f2bf(e4 * inv * (float)m1.x);
  o1.y = f2bf(e5 * inv * (float)m1.y);
  o1.z = f2bf(e6 * inv * (float)m1.z);
  o1.w = f2bf(e7 * inv * (float)m1.w);
  ((ushort4*)p)[t]       = o0;
  ((ushort4*)p)[t + 256] = o1;
}

extern "C" void kernel_launch(void* const* d_in, const int* in_sizes, int n_in,
                              void* d_out, int out_size, void* d_ws, size_t ws_size,
                              hipStream_t stream)
{
  (void)in_sizes; (void)n_in; (void)out_size;
  const float* kin  = (const float*)d_in[0];
  const float* qin  = (const float*)d_in[1];
  const float* Win  = (const float*)d_in[2];
  const int*   mask = (const int*)d_in[3];

  // ws: Wt (4MB) | per-batch { qsplit 8 | qwsplit 8 | ksplit 8 | kT 4 | S 16 | P 8 } = 52MB
  int bpc = 1;
  {
    const size_t per_b = (size_t)2048*2048*2*3 + (size_t)1024*2048*2
                       + (size_t)2048*2048*4 + (size_t)2048*2048*2;
    const size_t fixed = (size_t)1024*2048*2;
    const int cands[5] = {16, 8, 4, 2, 1};
    for (int i = 0; i < 5; ++i){
      if (fixed + (size_t)cands[i] * per_b <= ws_size){ bpc = cands[i]; break; }
    }
  }
  unsigned short* Wt      = (unsigned short*)d_ws;
  unsigned short* qsplit  = Wt + (size_t)1024*2048;
  unsigned short* qwsplit = qsplit  + (size_t)bpc*2048*2048;
  unsigned short* ksplit  = qwsplit + (size_t)bpc*2048*2048;
  unsigned short* kT      = ksplit  + (size_t)bpc*2048*2048;
  float*          Sb      = (float*)(kT + (size_t)bpc*1024*2048);
  unsigned short* Pb      = (unsigned short*)(Sb + (size_t)bpc*2048*2048);

  wtprep_kernel<<<dim3(16, 16, 1), 256, 0, stream>>>(Win, Wt);

  for (int cb = 0; cb < 16; cb += bpc){
    qprep_kernel<<<dim3(bpc * 1024, 1, 1), 256, 0, stream>>>(
        qin + (size_t)cb * 2048 * 1024, qsplit);

    // K1: qw = q @ W  (3-pass split via remap, NT=48) -> qwsplit [h|l]
    gemm256<1, 1><<<dim3(bpc * 8, 4, 1), 512, 0, stream>>>(
        qsplit, Wt, qwsplit, 48, 2048, 2048, 0, 0, 0, 0);

    kprep_kernel<<<dim3(32, 16, bpc), 256, 0, stream>>>(
        kin + (size_t)cb * 2048 * 1024, ksplit, kT);

    // K2: S = qw @ k^T (3-pass split via remap, NT=48), batched
    gemm256<1, 0><<<dim3(8, 8, bpc), 512, 0, stream>>>(
        qwsplit, ksplit, Sb, 48, 2048, 2048, 2048,
        (long)2048 * 2048, (long)2048 * 2048, (long)2048 * 2048);

    // K3: row softmax * mask -> P (bf16)
    softmax_kernel<<<dim3(bpc * 2048, 1, 1), 256, 0, stream>>>(
        Sb, mask + (size_t)cb * 2048 * 2048, Pb);

    // K4: O = P @ kT^T (plain, NT=32), batched -> d_out
    gemm256<0, 0><<<dim3(8, 4, bpc), 512, 0, stream>>>(
        Pb, kT, (float*)d_out + (size_t)cb * 2048 * 1024, 32, 2048, 2048, 1024,
        (long)2048 * 2048, (long)1024 * 2048, (long)2048 * 1024);
  }
}